// Round 2
// baseline (1289.646 us; speedup 1.0000x reference)
//
#include <hip/hip_runtime.h>

// UniformShardedEmbeddingBags: B=1024, T=32, D=64, E=100000, L=50
// out[b, :] = sum_{n in [off[b], off[b+1])} W[idx[n], b % T, :]
//
// Strategy: the bag-major gather is random-miss-bound (round-1 evidence:
// 4x fewer vmem instructions changed nothing -> per-CU miss-queue cap, not
// issue). Invert to e-major:
//   K0: zero cursors + out
//   K1: bin (e -> bag) records into per-e buckets (cursors/buckets in d_ws)
//   K2: sweep e ascending; read W[e,t,:] in address order (DRAM/L2 friendly),
//       atomicAdd 256B rows into the L2-resident 8.4MB output.
// Fallback to the harness-verified bag-major kernel if workspace/shape
// assumptions don't hold.

constexpr int kT   = 32;
constexpr int kD   = 64;
constexpr int kCap = 64;   // bucket capacity; Poisson(16.4) => P(overflow) ~ 1e-10

// ---------------- Phase 0: zero cursors and output ----------------
__global__ __launch_bounds__(256) void zero_kernel(
    int* __restrict__ cursors, int E,
    float* __restrict__ out, int out_elems)
{
    const int i      = blockIdx.x * 256 + threadIdx.x;
    const int stride = gridDim.x * 256;
    for (int k = i; k < E; k += stride) cursors[k] = 0;
    for (int k = i; k < out_elems; k += stride) out[k] = 0.f;
}

// ---------------- Phase 1: bin (e -> bag) ----------------
__global__ __launch_bounds__(256) void bin_kernel(
    const float* __restrict__ weights,
    const int*   __restrict__ features,
    const int*   __restrict__ offsets,
    int*            __restrict__ cursors,
    unsigned short* __restrict__ buckets,
    float*          __restrict__ out,
    int num_bags)
{
    const int gwave = (int)((blockIdx.x * 256u + threadIdx.x) >> 6);
    const int lane  = (int)(threadIdx.x & 63u);
    if (gwave >= num_bags) return;

    const int bag   = gwave;
    const int start = offsets[bag];
    const int end   = offsets[bag + 1];

    for (int n = start + lane; n < end; n += 64) {
        const int e    = features[n];
        const int slot = atomicAdd(&cursors[e], 1);
        if (slot < kCap) {
            buckets[(size_t)e * kCap + slot] = (unsigned short)bag;
        } else {
            // overflow fallback: direct accumulate (vanishingly rare)
            const int t = bag & (kT - 1);
            const float* w = weights + (size_t)e * (kT * kD) + (size_t)t * kD;
            float* o = out + (size_t)bag * kD;
            for (int d = 0; d < kD; ++d) {
                __hip_atomic_fetch_add(&o[d], w[d],
                    __ATOMIC_RELAXED, __HIP_MEMORY_SCOPE_AGENT);
            }
        }
    }
}

// ---------------- Phase 2: e-major sweep ----------------
__global__ __launch_bounds__(256) void sweep_kernel(
    const float* __restrict__ weights,
    const int*            __restrict__ cursors,
    const unsigned short* __restrict__ buckets,
    float* __restrict__ out,
    int E)
{
    const int gwave = (int)((blockIdx.x * 256u + threadIdx.x) >> 6);
    const int lane  = (int)(threadIdx.x & 63u);
    if (gwave >= E) return;

    const int e = gwave;
    int cnt = cursors[e];
    cnt = cnt < kCap ? cnt : kCap;
    if (cnt == 0) return;

    // lane j holds the j-th referencing bag; broadcast via shfl
    const int my = (lane < cnt) ? (int)buckets[(size_t)e * kCap + lane] : 0;

    const float* wbase = weights + (size_t)e * (kT * kD) + lane;

    int j = 0;
    // 2-wide software pipeline: both loads issued before the atomics
    for (; j + 2 <= cnt; j += 2) {
        const int bag0 = __shfl(my, j, 64);
        const int bag1 = __shfl(my, j + 1, 64);
        const int t0 = bag0 & (kT - 1);
        const int t1 = bag1 & (kT - 1);
        const float v0 = wbase[t0 * kD];
        const float v1 = wbase[t1 * kD];
        __hip_atomic_fetch_add(out + (size_t)bag0 * kD + lane, v0,
            __ATOMIC_RELAXED, __HIP_MEMORY_SCOPE_AGENT);
        __hip_atomic_fetch_add(out + (size_t)bag1 * kD + lane, v1,
            __ATOMIC_RELAXED, __HIP_MEMORY_SCOPE_AGENT);
    }
    if (j < cnt) {
        const int bag0 = __shfl(my, j, 64);
        const int t0 = bag0 & (kT - 1);
        const float v0 = wbase[t0 * kD];
        __hip_atomic_fetch_add(out + (size_t)bag0 * kD + lane, v0,
            __ATOMIC_RELAXED, __HIP_MEMORY_SCOPE_AGENT);
    }
}

// ---------------- Fallback: harness-verified bag-major kernel ----------------
__global__ __launch_bounds__(256) void embag_kernel(
    const float* __restrict__ weights,
    const int*   __restrict__ features,
    const int*   __restrict__ offsets,
    float*       __restrict__ out,
    int num_bags)
{
    const int gwave = (int)((blockIdx.x * 256u + threadIdx.x) >> 6);
    const int lane  = (int)(threadIdx.x & 63u);
    if (gwave >= num_bags) return;

    const int bag = gwave;
    const int t   = bag & (kT - 1);
    const float* wb = weights + (size_t)t * kD + lane;
    const size_t row_stride = (size_t)kT * kD;

    const int start = offsets[bag];
    const int end   = offsets[bag + 1];

    float a0 = 0.f, a1 = 0.f;
    int n = start;
    #pragma unroll 4
    for (; n + 2 <= end; n += 2) {
        const int e0 = features[n];
        const int e1 = features[n + 1];
        a0 += wb[(size_t)e0 * row_stride];
        a1 += wb[(size_t)e1 * row_stride];
    }
    if (n < end) {
        a0 += wb[(size_t)features[n] * row_stride];
    }
    out[(size_t)bag * kD + lane] = a0 + a1;
}

extern "C" void kernel_launch(void* const* d_in, const int* in_sizes, int n_in,
                              void* d_out, int out_size, void* d_ws, size_t ws_size,
                              hipStream_t stream) {
    const float* weights  = (const float*)d_in[0];
    const int*   features = (const int*)d_in[1];
    const int*   offsets  = (const int*)d_in[2];
    float*       out      = (float*)d_out;

    const int num_bags = in_sizes[2] - 1;            // B*T
    const int E        = in_sizes[0] / (kT * kD);    // weights is (E, T, D)

    // workspace layout: [cursors: E ints][buckets: E*kCap u16], 512B aligned
    const size_t cur_bytes = ((size_t)E * sizeof(int) + 511) & ~(size_t)511;
    const size_t bkt_bytes = (size_t)E * kCap * sizeof(unsigned short);
    const size_t need      = cur_bytes + bkt_bytes;

    const bool binned_ok =
        d_ws != nullptr && ws_size >= need &&
        num_bags > 0 && num_bags <= 65536 &&          // bag fits u16
        (size_t)E * (kT * kD) == (size_t)in_sizes[0]; // exact shape match

    if (binned_ok) {
        int* cursors = (int*)d_ws;
        unsigned short* buckets = (unsigned short*)((char*)d_ws + cur_bytes);
        const int out_elems = num_bags * kD;

        zero_kernel<<<2048, 256, 0, stream>>>(cursors, E, out, out_elems);

        const int bin_blocks = (num_bags * 64 + 255) / 256;
        bin_kernel<<<bin_blocks, 256, 0, stream>>>(
            weights, features, offsets, cursors, buckets, out, num_bags);

        const int sweep_blocks = (E * 64 + 255) / 256;
        sweep_kernel<<<sweep_blocks, 256, 0, stream>>>(
            weights, cursors, buckets, out, E);
    } else {
        const int blocks = (num_bags * 64 + 255) / 256;
        embag_kernel<<<blocks, 256, 0, stream>>>(
            weights, features, offsets, out, num_bags);
    }
}